// Round 1
// baseline (355.897 us; speedup 1.0000x reference)
//
#include <hip/hip_runtime.h>
#include <stdint.h>

// HeteroSTHN edge-predictor, fused bf16-MFMA implementation.
// pred[p,t] = out_W[t] . relu(h_src.src_W[t] + src_b[t] + h_dst.dst_W[t] + dst_b[t]) + out_b[t]
// out[p] = any(mask[p]) ? max_t(masked pred) : 0
//
// GEMM view per pair p: A row = [h_src | h_dst] (K=400 pad 448), B[t] = [src_W[t];dst_W[t]] (N=100 pad 112).
// A fragments in registers (reused across all 8 t); B staged per (t,slab) via global_load_lds from a
// prep-kernel-built bf16 buffer that is transposed ([j][k]) and XOR-swizzled for conflict-free ds_read_b128.

typedef float f32x4 __attribute__((ext_vector_type(4)));
typedef short s16x8 __attribute__((ext_vector_type(8)));

static constexpr int E_NODES  = 65536;
static constexpr int D_DIM    = 200;
static constexpr int H_DIM    = 100;
static constexpr int T_TYPES  = 8;
static constexpr int NPAD     = 112;            // padded H (7 x 16)
static constexpr int NT       = 7;              // N tiles of 16
static constexpr int NSLAB    = 7;              // K slabs of 64 (K = 448: src 0..199, dst 224..423, zeros elsewhere)
static constexpr int P_TILE   = 128;
static constexpr int THREADS  = 256;
static constexpr int RS_TOTAL = T_TYPES * NSLAB;      // 56 (t,slab) pairs
static constexpr int SLAB_BYTES = NPAD * 64 * 2;      // 14336 B per slab
static constexpr int SLAB_XFERS = SLAB_BYTES / 16;    // 896 x 16B transfers

__device__ unsigned short g_Wt[RS_TOTAL * NPAD * 64]; // bf16, transposed+swizzled LDS image
__device__ float g_bias[T_TYPES * NPAD];              // src_b + dst_b (0 pad)
__device__ float g_outw[T_TYPES * NPAD];              // out_W flat (0 pad)
__device__ float g_outb[T_TYPES];

__device__ __forceinline__ unsigned short f2bf(float f) {
  unsigned int u = __float_as_uint(f);
  u += 0x7FFFu + ((u >> 16) & 1u);   // round-to-nearest-even
  return (unsigned short)(u >> 16);
}

__global__ void prep_weights(const float* __restrict__ srcW, const float* __restrict__ dstW,
                             const float* __restrict__ srcB, const float* __restrict__ dstB,
                             const float* __restrict__ outW, const float* __restrict__ outB) {
  int idx = blockIdx.x * blockDim.x + threadIdx.x;
  const int total = RS_TOTAL * NPAD * 64;
  if (idx < total) {
    int kk   = idx & 63;
    int j    = (idx >> 6) % NPAD;
    int rs   = (idx >> 6) / NPAD;     // t*7 + slab
    int slab = rs % NSLAB;
    int t    = rs / NSLAB;
    int k    = slab * 64 + kk;
    float v = 0.0f;
    if (j < H_DIM) {
      if (k < D_DIM)                          v = srcW[(t * D_DIM + k) * H_DIM + j];
      else if (k >= 224 && k < 224 + D_DIM)   v = dstW[(t * D_DIM + (k - 224)) * H_DIM + j];
    }
    int kks = kk ^ ((j & 7) << 3);    // XOR bank swizzle baked into layout
    g_Wt[(rs * NPAD + j) * 64 + kks] = f2bf(v);
  }
  if (idx < T_TYPES * NPAD) {
    int t = idx / NPAD, j = idx % NPAD;
    float bb = 0.0f, ww = 0.0f;
    if (j < H_DIM) {
      bb = srcB[t * H_DIM + j] + dstB[t * H_DIM + j];
      ww = outW[t * H_DIM + j];
    }
    g_bias[idx] = bb;
    g_outw[idx] = ww;
    if (j == 0) g_outb[t] = outB[t];
  }
}

__device__ __forceinline__ void stage_B(int rs, unsigned short* dst, int tid) {
  char* src = (char*)g_Wt + (size_t)rs * SLAB_BYTES;
#pragma unroll
  for (int i = 0; i < 4; ++i) {
    int idx = i * THREADS + tid;
    if (idx < SLAB_XFERS) {   // last round: waves 0,1 fully active, waves 2,3 fully idle
      __builtin_amdgcn_global_load_lds(
          (const __attribute__((address_space(1))) void*)(src + idx * 16),
          (__attribute__((address_space(3))) void*)(dst + idx * 8),
          16, 0, 0);
    }
  }
}

__global__ __launch_bounds__(THREADS, 2)
void fused_pred(const float* __restrict__ h, const int* __restrict__ poss,
                float* __restrict__ out) {
  __shared__ __align__(16) unsigned short ldsB[2][NPAD * 64];   // 2 x 14336 B
  __shared__ __align__(16) int ldsMask[P_TILE * T_TYPES];       // 4 KB

  const int tid  = threadIdx.x;
  const int lane = tid & 63;
  const int w    = tid >> 6;       // wave id 0..3, owns rows [32w, 32w+32)
  const int c    = lane & 15;
  const int g    = lane >> 4;
  const int P0   = (int)blockIdx.x * P_TILE;

  // stage mask tile (pos rows are poss[:E], neg rows poss[E:], pair-indexed directly)
  {
    const int4* mp = (const int4*)(poss + (size_t)P0 * T_TYPES);
    ((int4*)ldsMask)[tid] = mp[tid];
  }

  stage_B(0, ldsB[0], tid);   // first B slab in flight under the A loads

  // A fragments in registers: A[mt][ks], k = ks*32 + g*8 + e
  // k in [0,200): src row; [224,424): dst row; zeros elsewhere.
  s16x8 A[2][14];
#pragma unroll
  for (int mt = 0; mt < 2; ++mt) {
    const int row = w * 32 + mt * 16 + c;
    const int p   = P0 + row;
    const float* sp = h + (size_t)(p & (E_NODES - 1)) * D_DIM;   // p % E (E = 2^16)
    const float* dp = h + ((size_t)E_NODES + (size_t)p) * D_DIM;
#pragma unroll
    for (int ks = 0; ks < 14; ++ks) {
      const float* base = (ks < 7) ? sp : dp;
      const int k0 = ((ks < 7) ? ks : (ks - 7)) * 32 + g * 8;
      s16x8 a = {};
      const bool valid = !((ks == 6 || ks == 13) && (g != 0));   // tail k in [192,200) only for g==0
      if (valid) {
        float4 f0 = *(const float4*)(base + k0);
        float4 f1 = *(const float4*)(base + k0 + 4);
        a[0] = (short)f2bf(f0.x); a[1] = (short)f2bf(f0.y);
        a[2] = (short)f2bf(f0.z); a[3] = (short)f2bf(f0.w);
        a[4] = (short)f2bf(f1.x); a[5] = (short)f2bf(f1.y);
        a[6] = (short)f2bf(f1.z); a[7] = (short)f2bf(f1.w);
      }
      A[mt][ks] = a;
    }
  }

  const f32x4 ZERO4 = {0.f, 0.f, 0.f, 0.f};
  f32x4 acc[2][NT];
#pragma unroll
  for (int mt = 0; mt < 2; ++mt)
#pragma unroll
    for (int nt = 0; nt < NT; ++nt) acc[mt][nt] = ZERO4;

  float runmax[2][4];
#pragma unroll
  for (int mt = 0; mt < 2; ++mt)
#pragma unroll
    for (int r = 0; r < 4; ++r) runmax[mt][r] = -1e30f;

  __syncthreads();   // slab 0 staged, mask ready

  int buf = 0;
  const int swz = (c & 7) << 4;
  for (int t = 0; t < T_TYPES; ++t) {
#pragma unroll
    for (int slab = 0; slab < NSLAB; ++slab) {
      const int s = t * NSLAB + slab;
      if (s + 1 < RS_TOTAL) stage_B(s + 1, ldsB[buf ^ 1], tid);   // async prefetch next slab

      const char* B = (const char*)ldsB[buf];
#pragma unroll
      for (int ksl = 0; ksl < 2; ++ksl) {
        const int koff = (ksl * 64 + g * 16) ^ swz;
        const s16x8 a0 = A[0][slab * 2 + ksl];
        const s16x8 a1 = A[1][slab * 2 + ksl];
#pragma unroll
        for (int nt = 0; nt < NT; ++nt) {
          s16x8 b = *(const s16x8*)(B + (nt * 16 + c) * 128 + koff);
          acc[0][nt] = __builtin_amdgcn_mfma_f32_16x16x32_bf16(a0, b, acc[0][nt], 0, 0, 0);
          acc[1][nt] = __builtin_amdgcn_mfma_f32_16x16x32_bf16(a1, b, acc[1][nt], 0, 0, 0);
        }
      }

      if (slab == NSLAB - 1) {
        // epilogue for this t: bias + relu + out_W dot, reduce over 16 col-lanes, masked max
        float bj[NT], wj[NT];
#pragma unroll
        for (int nt = 0; nt < NT; ++nt) {
          const int j = t * NPAD + nt * 16 + c;
          bj[nt] = g_bias[j];
          wj[nt] = g_outw[j];
        }
        const float outb = g_outb[t];
#pragma unroll
        for (int mt = 0; mt < 2; ++mt) {
#pragma unroll
          for (int r = 0; r < 4; ++r) {
            float v = 0.f;
#pragma unroll
            for (int nt = 0; nt < NT; ++nt)
              v += fmaxf(acc[mt][nt][r] + bj[nt], 0.f) * wj[nt];
            v += __shfl_xor(v, 1);
            v += __shfl_xor(v, 2);
            v += __shfl_xor(v, 4);
            v += __shfl_xor(v, 8);
            const float pred = v + outb;
            const int row = w * 32 + mt * 16 + g * 4 + r;   // C/D: row=(lane>>4)*4+reg, col=lane&15
            if (ldsMask[row * T_TYPES + t] != 0)
              runmax[mt][r] = fmaxf(runmax[mt][r], pred);
          }
#pragma unroll
          for (int nt = 0; nt < NT; ++nt) acc[mt][nt] = ZERO4;
        }
      }
      __syncthreads();
      buf ^= 1;
    }
  }

  if (c == 0) {
#pragma unroll
    for (int mt = 0; mt < 2; ++mt)
#pragma unroll
      for (int r = 0; r < 4; ++r) {
        const int row = w * 32 + mt * 16 + g * 4 + r;
        const float v = runmax[mt][r];
        out[P0 + row] = (v > -1e29f) ? v : 0.0f;   // where(any_valid, best, 0)
      }
  }
}

extern "C" void kernel_launch(void* const* d_in, const int* in_sizes, int n_in,
                              void* d_out, int out_size, void* d_ws, size_t ws_size,
                              hipStream_t stream) {
  const float* h    = (const float*)d_in[0];
  const float* srcW = (const float*)d_in[1];
  const float* srcB = (const float*)d_in[2];
  const float* dstW = (const float*)d_in[3];
  const float* dstB = (const float*)d_in[4];
  const float* outW = (const float*)d_in[5];
  const float* outB = (const float*)d_in[6];
  const int*   poss = (const int*)d_in[7];
  float* out = (float*)d_out;

  const int prep_total = RS_TOTAL * NPAD * 64;
  prep_weights<<<(prep_total + 255) / 256, 256, 0, stream>>>(srcW, dstW, srcB, dstB, outW, outB);

  const int nblocks = (2 * E_NODES) / P_TILE;   // 1024
  fused_pred<<<nblocks, THREADS, 0, stream>>>(h, poss, out);
}

// Round 6
// 328.930 us; speedup vs baseline: 1.0820x; 1.0820x over previous
//
#include <hip/hip_runtime.h>
#include <stdint.h>

// HeteroSTHN edge-predictor, fused bf16-MFMA, 2-phase issue-early pipeline (safe __syncthreads).
// pred[p,t] = out_W[t] . relu(h_src.src_W[t] + src_b[t] + h_dst.dst_W[t] + dst_b[t]) + out_b[t]
// out[p] = any(mask[p]) ? max_t(masked pred) : 0
//
// GEMM view: A row = [h_src | h_dst] merged K (src k<200, dst 200<=k<400, pad 416, staged 512),
// B[t] transposed [j][k], XOR-swizzled, pre-built by prep kernel. A in registers (reused across t);
// B double-buffered in LDS, staged per (t, K-128-interval) via global_load_lds ISSUED AT INTERVAL
// START so the interval's ds_read+MFMA covers the L2 latency; one __syncthreads() per interval
// (full fence: drains the just-issued stage AND closes the buffer-reuse race — no raw barriers,
// no exact vmcnt accounting; robust to spills/stray vmem).

typedef float f32x4 __attribute__((ext_vector_type(4)));
typedef short s16x8 __attribute__((ext_vector_type(8)));

static constexpr int E_NODES = 65536;
static constexpr int D_DIM   = 200;
static constexpr int H_DIM   = 100;
static constexpr int T_TYPES = 8;
static constexpr int NPAD    = 112;   // padded H (7 x 16)
static constexpr int NT      = 7;
static constexpr int KS      = 13;    // valid K sub-slabs of 32 (K=416 real, staged 512)
static constexpr int BK      = 128;   // K per stage interval
static constexpr int SLPT    = 4;     // intervals per t (4 x 128 = 512)
static constexpr int P_TILE  = 128;
static constexpr int THREADS = 256;
static constexpr int N_INT   = T_TYPES * SLPT;          // 32
static constexpr int SLAB_ELEMS = NPAD * BK;            // 14336 bf16 = 28672 B
static constexpr int XFERS_PT   = SLAB_ELEMS * 2 / 16 / THREADS;  // 7 (uniform)

__device__ unsigned short g_Wt[N_INT * SLAB_ELEMS];     // 918 KB bf16, swizzled LDS image

__device__ __forceinline__ unsigned short f2bf(float f) {
  unsigned int u = __float_as_uint(f);
  u += 0x7FFFu + ((u >> 16) & 1u);
  return (unsigned short)(u >> 16);
}

__global__ void prep_weights(const float* __restrict__ srcW, const float* __restrict__ dstW) {
  int idx = blockIdx.x * blockDim.x + threadIdx.x;   // j-inner for coalesced W reads
  const int total = N_INT * SLAB_ELEMS;
  if (idx >= total) return;
  int j   = idx % NPAD;
  int rem = idx / NPAD;
  int kk  = rem % BK;
  int rs  = rem / BK;          // t*4 + sl
  int sl  = rs & 3;
  int t   = rs >> 2;
  int k   = sl * BK + kk;      // merged K: [0,200) src, [200,400) dst, else 0
  float v = 0.0f;
  if (j < H_DIM) {
    if (k < D_DIM)            v = srcW[(t * D_DIM + k) * H_DIM + j];
    else if (k < 2 * D_DIM)   v = dstW[(t * D_DIM + (k - D_DIM)) * H_DIM + j];
  }
  int kks = kk ^ ((j & 7) << 3);   // XOR bank swizzle baked into the image
  g_Wt[(rs * NPAD + j) * BK + kks] = f2bf(v);
}

__device__ __forceinline__ void stage(int rs, unsigned short* dst, int tid) {
  const char* src = (const char*)g_Wt + (size_t)rs * SLAB_ELEMS * 2;
  char* d = (char*)dst;
#pragma unroll
  for (int i = 0; i < XFERS_PT; ++i) {
    const int off = (i * THREADS + tid) * 16;
    __builtin_amdgcn_global_load_lds(
        (const __attribute__((address_space(1))) void*)(src + off),
        (__attribute__((address_space(3))) void*)(d + off),
        16, 0, 0);
  }
}

__global__ __launch_bounds__(THREADS, 2)
void fused_pred(const float* __restrict__ h,
                const float* __restrict__ srcB, const float* __restrict__ dstB,
                const float* __restrict__ outW, const float* __restrict__ outB,
                const int* __restrict__ poss, float* __restrict__ out) {
  __shared__ __align__(16) unsigned short ldsB[2][SLAB_ELEMS];  // 2 x 28672 B
  __shared__ __align__(16) int   ldsMask[P_TILE * T_TYPES];     // 4 KB
  __shared__ float ldsBias[T_TYPES * NPAD];                     // 3.5 KB
  __shared__ float ldsOutw[T_TYPES * NPAD];                     // 3.5 KB
  __shared__ float ldsOutb[T_TYPES];

  const int tid  = threadIdx.x;
  const int lane = tid & 63;
  const int w    = tid >> 6;
  const int c    = lane & 15;
  const int g    = lane >> 4;

  // XCD-paired remap: per-XCD chunks; pos/neg tiles over the same src rows are adjacent.
  const int l     = ((int)blockIdx.x & 7) * 128 + ((int)blockIdx.x >> 3);
  const int which = l & 1;
  const int grp   = l >> 1;
  const int P0    = which * E_NODES + grp * P_TILE;

  // Slab 0 in flight under the whole prologue.
  stage(0, ldsB[0], tid);
  __builtin_amdgcn_sched_barrier(0);

  // constants -> LDS (epilogue reads LDS only)
#pragma unroll
  for (int i = 0; i < 4; ++i) {
    int idx = i * THREADS + tid;
    if (idx < T_TYPES * NPAD) {
      int t = idx / NPAD, j = idx - t * NPAD;
      float bb = 0.f, ww = 0.f;
      if (j < H_DIM) {
        bb = srcB[t * H_DIM + j] + dstB[t * H_DIM + j];
        ww = outW[t * H_DIM + j];
      }
      ldsBias[idx] = bb;
      ldsOutw[idx] = ww;
    }
  }
  if (tid < T_TYPES) ldsOutb[tid] = outB[tid];
  ((int4*)ldsMask)[tid] = ((const int4*)(poss + (size_t)P0 * T_TYPES))[tid];

  // A fragments in registers: A[mt][ks], merged K, k = ks*32 + g*8 + e
  s16x8 A[2][KS];
#pragma unroll
  for (int mt = 0; mt < 2; ++mt) {
    const int row = w * 32 + mt * 16 + c;
    const int p   = P0 + row;
    const float* sp = h + (size_t)(p & (E_NODES - 1)) * D_DIM;
    const float* dp = h + ((size_t)E_NODES + (size_t)p) * D_DIM;
#pragma unroll
    for (int ks = 0; ks < KS; ++ks) {
      const int k0 = ks * 32 + g * 8;
      s16x8 a = {};
      if (k0 < 2 * D_DIM) {                 // only ks=12, g>=2 invalid (pad)
        const float* base = (k0 < D_DIM) ? (sp + k0) : (dp + (k0 - D_DIM));
        float4 f0 = *(const float4*)(base);
        float4 f1 = *(const float4*)(base + 4);
        a[0] = (short)f2bf(f0.x); a[1] = (short)f2bf(f0.y);
        a[2] = (short)f2bf(f0.z); a[3] = (short)f2bf(f0.w);
        a[4] = (short)f2bf(f1.x); a[5] = (short)f2bf(f1.y);
        a[6] = (short)f2bf(f1.z); a[7] = (short)f2bf(f1.w);
      }
      A[mt][ks] = a;
    }
  }

  const f32x4 ZERO4 = {0.f, 0.f, 0.f, 0.f};
  f32x4 acc[2][NT];
  float runmax[2][4];
#pragma unroll
  for (int mt = 0; mt < 2; ++mt) {
#pragma unroll
    for (int nt = 0; nt < NT; ++nt) acc[mt][nt] = ZERO4;
#pragma unroll
    for (int r = 0; r < 4; ++r) runmax[mt][r] = -1e30f;
  }

  const int swz = (c & 7) << 4;

  __syncthreads();   // slab 0 staged (vmcnt(0) drain), constants/mask visible

  for (int t = 0; t < T_TYPES; ++t) {
#pragma unroll
    for (int sl = 0; sl < SLPT; ++sl) {
      // ---- issue next slab FIRST: its latency hides under this interval's compute;
      //      the end-of-interval __syncthreads drains it (and fences buffer reuse).
      if (sl < SLPT - 1 || t < T_TYPES - 1)
        stage(t * SLPT + sl + 1, ldsB[(sl + 1) & 1], tid);
      __builtin_amdgcn_sched_barrier(0);

      const char* B = (const char*)ldsB[sl & 1];
#pragma unroll
      for (int ksl = 0; ksl < 4; ++ksl) {
        const int ksg = sl * 4 + ksl;
        if (ksg < KS) {
          const int koff = (ksl * 64 + g * 16) ^ swz;
          const s16x8 a0 = A[0][ksg];
          const s16x8 a1 = A[1][ksg];
#pragma unroll
          for (int nt = 0; nt < NT; ++nt) {
            s16x8 b = *(const s16x8*)(B + (nt * 16 + c) * 256 + koff);
            acc[0][nt] = __builtin_amdgcn_mfma_f32_16x16x32_bf16(a0, b, acc[0][nt], 0, 0, 0);
            acc[1][nt] = __builtin_amdgcn_mfma_f32_16x16x32_bf16(a1, b, acc[1][nt], 0, 0, 0);
          }
        }
      }

      if (sl == SLPT - 1) {
        // epilogue for t: bias+relu+outW dot, 16-lane reduce, masked running max.
        // Reads regs + stable LDS regions only; overlaps the in-flight next-t stage.
        float bj[NT], wj[NT];
#pragma unroll
        for (int nt = 0; nt < NT; ++nt) {
          bj[nt] = ldsBias[t * NPAD + nt * 16 + c];
          wj[nt] = ldsOutw[t * NPAD + nt * 16 + c];
        }
        const float ob = ldsOutb[t];
#pragma unroll
        for (int mt = 0; mt < 2; ++mt) {
#pragma unroll
          for (int r = 0; r < 4; ++r) {
            float v = 0.f;
#pragma unroll
            for (int nt = 0; nt < NT; ++nt)
              v += fmaxf(acc[mt][nt][r] + bj[nt], 0.f) * wj[nt];
            v += __shfl_xor(v, 1);
            v += __shfl_xor(v, 2);
            v += __shfl_xor(v, 4);
            v += __shfl_xor(v, 8);
            const float pred = v + ob;
            const int row = w * 32 + mt * 16 + g * 4 + r;   // C/D: row=(lane>>4)*4+reg, col=lane&15
            if (ldsMask[row * T_TYPES + t] != 0)
              runmax[mt][r] = fmaxf(runmax[mt][r], pred);
          }
#pragma unroll
          for (int nt = 0; nt < NT; ++nt) acc[mt][nt] = ZERO4;
        }
      }

      __syncthreads();   // drains stage(s+1); all waves done reading ldsB[sl&1]
    }
  }

  if (c == 0) {
#pragma unroll
    for (int mt = 0; mt < 2; ++mt)
#pragma unroll
      for (int r = 0; r < 4; ++r) {
        const int row = w * 32 + mt * 16 + g * 4 + r;
        const float v = runmax[mt][r];
        out[P0 + row] = (v > -1e29f) ? v : 0.0f;   // where(any_valid, best, 0)
      }
  }
}

extern "C" void kernel_launch(void* const* d_in, const int* in_sizes, int n_in,
                              void* d_out, int out_size, void* d_ws, size_t ws_size,
                              hipStream_t stream) {
  const float* h    = (const float*)d_in[0];
  const float* srcW = (const float*)d_in[1];
  const float* srcB = (const float*)d_in[2];
  const float* dstW = (const float*)d_in[3];
  const float* dstB = (const float*)d_in[4];
  const float* outW = (const float*)d_in[5];
  const float* outB = (const float*)d_in[6];
  const int*   poss = (const int*)d_in[7];
  float* out = (float*)d_out;

  const int prep_total = N_INT * SLAB_ELEMS;
  prep_weights<<<(prep_total + 255) / 256, 256, 0, stream>>>(srcW, dstW);

  const int nblocks = (2 * E_NODES) / P_TILE;   // 1024
  fused_pred<<<nblocks, THREADS, 0, stream>>>(h, srcB, dstB, outW, outB, poss, out);
}